// Round 11
// baseline (1433.193 us; speedup 1.0000x reference)
//
#include <hip/hip_runtime.h>

#define NENT 40000
#define NB 128
#define NQ 24
#define NOPS 12
#define EPO 300000
#define NTOT (NOPS * EPO)
#define NRANK 3
#define NPASS 8
#define CP 16       // batch columns per pass
#define ECAP 160    // ELL row capacity (Poisson(90) max over 40K rows << 160)

typedef float v4f __attribute__((ext_vector_type(4)));

__device__ __forceinline__ v4f shfl_xor4(v4f x, int m) {
    v4f r;
    r.x = __shfl_xor(x.x, m);
    r.y = __shfl_xor(x.y, m);
    r.z = __shfl_xor(x.z, m);
    r.w = __shfl_xor(x.w, m);
    return r;
}

__device__ __forceinline__ bool bittest(const unsigned* bm, int i) {
    return (bm[i >> 5] >> (i & 31)) & 1u;
}

// ---------------- bitmaps: heads and heads ∪ N_out(heads) ----------------
__global__ void headmark_kernel(const int* __restrict__ heads, unsigned* __restrict__ bmH,
                                unsigned* __restrict__ bm2) {
    int h = heads[threadIdx.x];
    atomicOr(&bmH[h >> 5], 1u << (h & 31));
    atomicOr(&bm2[h >> 5], 1u << (h & 31));
}

__global__ void mark2_kernel(const int* __restrict__ src, const int* __restrict__ dst,
                             const unsigned* __restrict__ bmH, unsigned* __restrict__ bm2) {
    int i = blockIdx.x * 256 + threadIdx.x;
    if (i < NTOT) {
        int s = src[i];
        if (bittest(bmH, s)) {
            int d = dst[i];
            atomicOr(&bm2[d >> 5], 1u << (d & 31));
        }
    }
}

// ---------------- single-pass ELL build: dst always; src gated on bm2 ----------------
__global__ void build_ell_kernel(const int* __restrict__ src, const int* __restrict__ dst,
                                 const float* __restrict__ val, const unsigned* __restrict__ bm2,
                                 int* __restrict__ fillD, int* __restrict__ fillS,
                                 int2* __restrict__ eD, int2* __restrict__ eS) {
    int i = blockIdx.x * 256 + threadIdx.x;
    if (i >= NTOT) return;
    int s = src[i], d = dst[i];
    int op = i / EPO;   // compile-time magic-mul
    int v = __float_as_int(val[i]);
    int pd = atomicAdd(&fillD[d], 1);
    eD[(size_t)d * ECAP + pd] = make_int2(s | (op << 16), v);
    if (bittest(bm2, s)) {
        int ps = atomicAdd(&fillS[s], 1);
        eS[(size_t)s * ECAP + ps] = make_int2(d | (op << 16), v);
    }
}

// ---------------- LSTM (deduped over 24 distinct query values) ----------------
__global__ void zxq_kernel(const float* __restrict__ emb,
                           const float* __restrict__ Wih_f, const float* __restrict__ bih_f,
                           const float* __restrict__ bhh_f,
                           const float* __restrict__ Wih_b, const float* __restrict__ bih_b,
                           const float* __restrict__ bhh_b,
                           float* __restrict__ zxq) {
    int combo = blockIdx.x / NQ;
    int q = blockIdx.x % NQ;
    int dir = combo / 3, r = combo % 3;
    const float* Wih = (dir ? Wih_b : Wih_f) + r * 512 * 128;
    const float* bih = (dir ? bih_b : bih_f) + r * 512;
    const float* bhh = (dir ? bhh_b : bhh_f) + r * 512;
    __shared__ float x[128];
    int u = threadIdx.x;
    x[u] = emb[q * 128 + u];
    __syncthreads();
    const float* W0p = Wih + u * 128;
    const float* W1p = Wih + (128 + u) * 128;
    const float* W2p = Wih + (256 + u) * 128;
    const float* W3p = Wih + (384 + u) * 128;
    float a0 = 0.f, a1 = 0.f, a2 = 0.f, a3 = 0.f;
    for (int d = 0; d < 128; ++d) {
        float xv = x[d];
        a0 = fmaf(xv, W0p[d], a0);
        a1 = fmaf(xv, W1p[d], a1);
        a2 = fmaf(xv, W2p[d], a2);
        a3 = fmaf(xv, W3p[d], a3);
    }
    float* o = zxq + (size_t)(combo * NQ + q) * 512;
    o[u]       = a0 + bih[u]       + bhh[u];
    o[128 + u] = a1 + bih[128 + u] + bhh[128 + u];
    o[256 + u] = a2 + bih[256 + u] + bhh[256 + u];
    o[384 + u] = a3 + bih[384 + u] + bhh[384 + u];
}

__global__ void lstmq_kernel(const float* __restrict__ Whh_f, const float* __restrict__ Whh_b,
                             const float* __restrict__ zxq, float* __restrict__ hq) {
    int combo = blockIdx.x / NQ;
    int q = blockIdx.x % NQ;
    int dir = combo / 3, r = combo % 3;
    const float* Whh = (dir ? Whh_b : Whh_f) + r * 512 * 128;
    __shared__ float h[128];
    int u = threadIdx.x;
    const float* z = zxq + (size_t)(combo * NQ + q) * 512;
    float zi0 = z[u], zf0 = z[128 + u], zg0 = z[256 + u], zo0 = z[384 + u];
    const float* Wi = Whh + u * 128;
    const float* Wf = Whh + (128 + u) * 128;
    const float* Wg = Whh + (256 + u) * 128;
    const float* Wo = Whh + (384 + u) * 128;
    float c = 0.f;
    h[u] = 0.f;
    for (int s = 0; s < 3; ++s) {
        __syncthreads();
        float a0 = 0.f, a1 = 0.f, a2 = 0.f, a3 = 0.f;
        for (int d = 0; d < 128; ++d) {
            float hv = h[d];
            a0 = fmaf(hv, Wi[d], a0);
            a1 = fmaf(hv, Wf[d], a1);
            a2 = fmaf(hv, Wg[d], a2);
            a3 = fmaf(hv, Wo[d], a3);
        }
        float ig = 1.f / (1.f + expf(-(zi0 + a0)));
        float fg = 1.f / (1.f + expf(-(zf0 + a1)));
        float gg = tanhf(zg0 + a2);
        float og = 1.f / (1.f + expf(-(zo0 + a3)));
        c = fg * c + ig * gg;
        float hn = og * tanhf(c);
        __syncthreads();
        h[u] = hn;
        hq[(size_t)((combo * 3 + s) * NQ + q) * 128 + u] = hn;
    }
}

__global__ void attnq_kernel(const float* __restrict__ hq, const float* __restrict__ W0,
                             const float* __restrict__ b0, float* __restrict__ attnq) {
    int r = blockIdx.x / 3, t = blockIdx.x % 3;
    __shared__ float W0s[256 * 13];
    for (int idx = threadIdx.x; idx < 256 * 13; idx += 32) W0s[idx] = W0[idx];
    __syncthreads();
    int q = threadIdx.x;
    if (q >= NQ) return;
    float acc[13];
    for (int k = 0; k < 13; ++k) acc[k] = b0[k];
    const float* hf = hq + (size_t)(((0 * 3 + r) * 3 + t) * NQ + q) * 128;
    const float* hb = hq + (size_t)(((1 * 3 + r) * 3 + (2 - t)) * NQ + q) * 128;
    for (int u = 0; u < 128; ++u) {
        float v = hf[u];
        for (int k = 0; k < 13; ++k) acc[k] = fmaf(v, W0s[u * 13 + k], acc[k]);
    }
    for (int u = 0; u < 128; ++u) {
        float v = hb[u];
        for (int k = 0; k < 13; ++k) acc[k] = fmaf(v, W0s[(128 + u) * 13 + k], acc[k]);
    }
    float m = acc[0];
    for (int k = 1; k < 13; ++k) m = fmaxf(m, acc[k]);
    float e[13];
    float sum = 0.f;
    for (int k = 0; k < 13; ++k) { e[k] = expf(acc[k] - m); sum += e[k]; }
    float inv = 1.f / sum;
    float* ao = attnq + (size_t)(r * 3 + t) * 13 * NQ;
    for (int k = 0; k < 13; ++k) ao[k * NQ + q] = e[k] * inv;
}

__global__ void expand_kernel(const int* __restrict__ queries, const float* __restrict__ attnq,
                              float* __restrict__ attn) {
    __shared__ int qs[128];
    if (threadIdx.x < 128) qs[threadIdx.x] = queries[threadIdx.x];
    __syncthreads();
    for (int idx = threadIdx.x; idx < 9 * 13 * 128; idx += 256) {
        int b = idx & 127, kk = idx >> 7;
        attn[idx] = attnq[kk * NQ + qs[b]];
    }
}

// ---------------- steps 0+1, sparse expansion over ELL-S; writes pass-major mem[r][p][j][c] ----------------
// 256 threads, 8-lane groups per source entry; z-chunked grid for occupancy.
__global__ void fused01_kernel(const int* __restrict__ heads, const float* __restrict__ attn,
                               const int* __restrict__ fillS, const int2* __restrict__ eS,
                               float* __restrict__ mem2) {
    int r = blockIdx.y;
    int b = blockIdx.x;
    int chunk = blockIdx.z;   // 0..1
    __shared__ float c0s[13], c1s[13];
    if (threadIdx.x < 13) {
        c0s[threadIdx.x] = attn[(size_t)((r * 3 + 0) * 13 + threadIdx.x) * 128 + b];
        c1s[threadIdx.x] = attn[(size_t)((r * 3 + 1) * 13 + threadIdx.x) * 128 + b];
    }
    __syncthreads();
    int h = heads[b];
    int lenH = fillS[h];
    float* mem = mem2 + ((size_t)(r * NPASS + (b >> 4)) * NENT) * CP + (b & 15);
    int g = threadIdx.x >> 3, lane8 = threadIdx.x & 7;   // 32 groups of 8 lanes
    for (int ent = g + chunk * 32; ent < lenH + 1; ent += 64) {
        int i; float wv;
        if (ent == 0) { i = h; wv = c0s[12]; }
        else {
            int2 e = eS[(size_t)h * ECAP + ent - 1];
            i = e.x & 0xFFFF;
            wv = __int_as_float(e.y) * c0s[e.x >> 16];
        }
        if (lane8 == 0) atomicAdd(&mem[(size_t)i * CP], c1s[12] * wv);
        int lenI = fillS[i];
        const int2* ei = eS + (size_t)i * ECAP;
        for (int f = lane8; f < lenI; f += 8) {
            int2 e2 = ei[f];
            atomicAdd(&mem[(size_t)(e2.x & 0xFFFF) * CP],
                      __int_as_float(e2.y) * c1s[e2.x >> 16] * wv);
        }
    }
}

// ---------------- step 2: dense gather, ALL 3 RANKS FUSED per block ----------------
// Per edge: 1 edge load + 1 unpack/mask + shared voffset -> 3 gathers (one per rank slice,
// same VGPR offset, different SGPR base) + 3 ds_read_b128 at +0/+1040/+2080 + 3x8 fma.
// Cuts per-edge VALU overhead ~2.4x and edge L2 traffic 3x vs per-rank grid.
#define CSR 260   // cs rank stride in floats (13*20)

#define CONSUME_ROW(E, W, T) { \
    int row = E.x & 0xFFFF; \
    v4f g0 = *(const v4f*)(inr0 + (size_t)row * CP + cq4); \
    v4f g1 = *(const v4f*)(inr1 + (size_t)row * CP + cq4); \
    v4f g2 = *(const v4f*)(inr2 + (size_t)row * CP + cq4); \
    int cb = (E.x >> 16) * 20 + cq4; \
    acc0##T += (W * *(const v4f*)&cs[cb]) * g0; \
    acc1##T += (W * *(const v4f*)&cs[CSR + cb]) * g1; \
    acc2##T += (W * *(const v4f*)&cs[2 * CSR + cb]) * g2; }

#define REDUCE_ONE(A, INR, OUTR, CID, RS, T) { \
    v4f red = A; \
    red += shfl_xor4(red, 4); \
    red += shfl_xor4(red, 8); \
    red += shfl_xor4(red, 16); \
    red += shfl_xor4(red, 32); \
    if (slot == 0) { \
        int j = jw + (T); \
        v4f mi = *(const v4f*)(INR + (size_t)j * CP + cq4); \
        v4f res = CID * mi + red; \
        *(v4f*)(OUTR + (size_t)j * CP + cq4) = res; \
        RS += res; \
    } }

__global__ __launch_bounds__(256) void dense_kernel(const float* __restrict__ attn,
                                                    const int* __restrict__ fillD,
                                                    const int2* __restrict__ edgesD,
                                                    const float* __restrict__ in,
                                                    float* __restrict__ out,
                                                    float* __restrict__ normv) {
    int p = blockIdx.x;   // pass = XCD (linear-id % 8, grid.x = 8 -> perfect pinning)
    __shared__ __align__(16) float cs[3 * CSR];      // [rank][op][20], rows 16B-aligned
    __shared__ float npart[3][4][16];
    int tid = threadIdx.x;
    if (tid < 13 * 16) {
        int op = tid >> 4, c0 = tid & 15;
#pragma unroll
        for (int r = 0; r < 3; ++r)
            cs[r * CSR + op * 20 + c0] =
                attn[(size_t)((r * 3 + 2) * 13 + op) * 128 + p * CP + c0];
    }
    __syncthreads();
    int wave = tid >> 6, lane = tid & 63;
    int slot = lane >> 2;        // 16 edge slots
    int cq4 = (lane & 3) * 4;    // 4 cols per lane
    int jw = blockIdx.y * 16 + wave * 4;   // 4 rows per wave
    const float* inr0 = in + (size_t)(0 * NPASS + p) * NENT * CP;
    const float* inr1 = in + (size_t)(1 * NPASS + p) * NENT * CP;
    const float* inr2 = in + (size_t)(2 * NPASS + p) * NENT * CP;
    float* outr0 = out + (size_t)(0 * NPASS + p) * NENT * CP;
    float* outr1 = out + (size_t)(1 * NPASS + p) * NENT * CP;
    float* outr2 = out + (size_t)(2 * NPASS + p) * NENT * CP;
    int l0 = fillD[jw], l1 = fillD[jw + 1], l2 = fillD[jw + 2], l3 = fillD[jw + 3];
    const int2* edp0 = edgesD + (size_t)(jw + 0) * ECAP;
    const int2* edp1 = edgesD + (size_t)(jw + 1) * ECAP;
    const int2* edp2 = edgesD + (size_t)(jw + 2) * ECAP;
    const int2* edp3 = edgesD + (size_t)(jw + 3) * ECAP;
    int maxlen = max(max(l0, l1), max(l2, l3));

    v4f acc00 = (v4f)0.f, acc01 = (v4f)0.f, acc02 = (v4f)0.f, acc03 = (v4f)0.f;
    v4f acc10 = (v4f)0.f, acc11 = (v4f)0.f, acc12 = (v4f)0.f, acc13 = (v4f)0.f;
    v4f acc20 = (v4f)0.f, acc21 = (v4f)0.f, acc22 = (v4f)0.f, acc23 = (v4f)0.f;

    for (int base = 0; base < maxlen; base += 16) {
        int bi = base + slot;
        // 4 edge loads (16 slots x 8B contiguous per row; 4 lanes/slot broadcast)
        int2 e0 = edp0[bi < l0 ? bi : 0];
        int2 e1 = edp1[bi < l1 ? bi : 0];
        int2 e2 = edp2[bi < l2 ? bi : 0];
        int2 e3 = edp3[bi < l3 ? bi : 0];
        float w0 = bi < l0 ? __int_as_float(e0.y) : 0.f;
        float w1 = bi < l1 ? __int_as_float(e1.y) : 0.f;
        float w2 = bi < l2 ? __int_as_float(e2.y) : 0.f;
        float w3 = bi < l3 ? __int_as_float(e3.y) : 0.f;
        // 12 gathers (3 ranks x 4 rows, shared voffset per row) + 12 LDS cc reads + 24 fma/mul
        CONSUME_ROW(e0, w0, 0)
        CONSUME_ROW(e1, w1, 1)
        CONSUME_ROW(e2, w2, 2)
        CONSUME_ROW(e3, w3, 3)
    }

    v4f cid0 = *(const v4f*)&cs[12 * 20 + cq4];
    v4f cid1 = *(const v4f*)&cs[CSR + 12 * 20 + cq4];
    v4f cid2 = *(const v4f*)&cs[2 * CSR + 12 * 20 + cq4];
    v4f rs0 = (v4f)0.f, rs1 = (v4f)0.f, rs2 = (v4f)0.f;
    REDUCE_ONE(acc00, inr0, outr0, cid0, rs0, 0)
    REDUCE_ONE(acc01, inr0, outr0, cid0, rs0, 1)
    REDUCE_ONE(acc02, inr0, outr0, cid0, rs0, 2)
    REDUCE_ONE(acc03, inr0, outr0, cid0, rs0, 3)
    REDUCE_ONE(acc10, inr1, outr1, cid1, rs1, 0)
    REDUCE_ONE(acc11, inr1, outr1, cid1, rs1, 1)
    REDUCE_ONE(acc12, inr1, outr1, cid1, rs1, 2)
    REDUCE_ONE(acc13, inr1, outr1, cid1, rs1, 3)
    REDUCE_ONE(acc20, inr2, outr2, cid2, rs2, 0)
    REDUCE_ONE(acc21, inr2, outr2, cid2, rs2, 1)
    REDUCE_ONE(acc22, inr2, outr2, cid2, rs2, 2)
    REDUCE_ONE(acc23, inr2, outr2, cid2, rs2, 3)
    if (slot == 0) {
        *(v4f*)&npart[0][wave][cq4] = rs0;
        *(v4f*)&npart[1][wave][cq4] = rs1;
        *(v4f*)&npart[2][wave][cq4] = rs2;
    }
    __syncthreads();
    if (tid < 48) {
        int r = tid >> 4, c = tid & 15;
        float s = npart[r][0][c] + npart[r][1][c] + npart[r][2][c] + npart[r][3][c];
        atomicAdd(&normv[r * 128 + p * CP + c], s);
    }
}

// ---------------- epilogue ----------------
__global__ void rnorm_kernel(const float* __restrict__ normv, float* __restrict__ rnormv) {
    int i = threadIdx.x;
    rnormv[i] = 1.f / fmaxf(normv[i], 1e-20f);
}

__global__ void final_kernel(const float* __restrict__ mem3, const float* __restrict__ rnormv,
                             float* __restrict__ out) {
    __shared__ float tile[32 * 129];
    __shared__ float rn[384];
    for (int idx = threadIdx.x; idx < 384; idx += 256) rn[idx] = rnormv[idx];
    __syncthreads();
    int j0 = blockIdx.x * 32;
    for (int p = 0; p < NPASS; ++p) {
        for (int it = 0; it < 2; ++it) {
            int lin = it * 256 + threadIdx.x;
            int jj = lin >> 4, c = lin & 15;
            int b = p * CP + c;
            float s = 0.f;
            for (int r = 0; r < 3; ++r)
                s += mem3[((size_t)(r * NPASS + p) * NENT + j0 + jj) * CP + c] * rn[r * 128 + b];
            tile[jj * 129 + b] = s;
        }
    }
    __syncthreads();
    for (int it = 0; it < 16; ++it) {
        int lin = it * 256 + threadIdx.x;
        int b = lin >> 5, jj = lin & 31;
        out[(size_t)b * NENT + j0 + jj] = tile[jj * 129 + b];
    }
}

extern "C" void kernel_launch(void* const* d_in, const int* in_sizes, int n_in,
                              void* d_out, int out_size, void* d_ws, size_t ws_size,
                              hipStream_t stream) {
    const int*   queries  = (const int*)d_in[0];
    const int*   heads    = (const int*)d_in[1];
    const int*   edge_src = (const int*)d_in[2];
    const int*   edge_dst = (const int*)d_in[3];
    const float* edge_val = (const float*)d_in[4];
    const float* emb      = (const float*)d_in[5];
    const float* Wih_f    = (const float*)d_in[6];
    const float* Whh_f    = (const float*)d_in[7];
    const float* bih_f    = (const float*)d_in[8];
    const float* bhh_f    = (const float*)d_in[9];
    const float* Wih_b    = (const float*)d_in[10];
    const float* Whh_b    = (const float*)d_in[11];
    const float* bih_b    = (const float*)d_in[12];
    const float* bhh_b    = (const float*)d_in[13];
    const float* W0       = (const float*)d_in[14];
    const float* b0       = (const float*)d_in[15];
    float* out = (float*)d_out;

    char* w = (char*)d_ws;
    size_t off = 0;
    auto alloc = [&](size_t bytes) -> void* {
        off = (off + 255) & ~(size_t)255;
        void* p = w + off;
        off += bytes;
        return p;
    };
    float* attnq  = (float*)alloc((size_t)9 * 13 * NQ * sizeof(float));
    float* attn   = (float*)alloc((size_t)9 * 13 * 128 * sizeof(float));
    float* zxq    = (float*)alloc((size_t)6 * NQ * 512 * sizeof(float));
    float* hq     = (float*)alloc((size_t)6 * 3 * NQ * 128 * sizeof(float));
    // meta block (single memset): bmH | bm2 | fillD | fillS
    unsigned* bmH = (unsigned*)alloc((2 * 1250 + 2 * NENT) * sizeof(int));
    unsigned* bm2 = bmH + 1250;
    int* fillD    = (int*)(bm2 + 1250);
    int* fillS    = fillD + NENT;
    int2*  eD     = (int2*)alloc((size_t)NENT * ECAP * sizeof(int2));
    float* mem2   = (float*)alloc((size_t)NRANK * NENT * NB * sizeof(float));
    float* mem3   = (float*)alloc((size_t)NRANK * NENT * NB * sizeof(float));
    int2*  eS     = (int2*)mem3;   // alias: eS lifetime (build..fused01) ends before mem3's (dense..final)
    float* normv  = (float*)alloc((size_t)NRANK * NB * sizeof(float));
    float* rnormv = (float*)alloc((size_t)NRANK * NB * sizeof(float));

    int cooGrid = (NTOT + 255) / 256;

    // bitmaps + fills (one memset), then single-pass ELL build
    hipMemsetAsync(bmH, 0, (2 * 1250 + 2 * NENT) * sizeof(int), stream);
    headmark_kernel<<<1, 128, 0, stream>>>(heads, bmH, bm2);
    mark2_kernel<<<cooGrid, 256, 0, stream>>>(edge_src, edge_dst, bmH, bm2);
    build_ell_kernel<<<cooGrid, 256, 0, stream>>>(edge_src, edge_dst, edge_val, bm2,
                                                  fillD, fillS, eD, eS);

    // LSTM + attention (deduped over 24 queries)
    zxq_kernel<<<6 * NQ, 128, 0, stream>>>(emb, Wih_f, bih_f, bhh_f, Wih_b, bih_b, bhh_b, zxq);
    lstmq_kernel<<<6 * NQ, 128, 0, stream>>>(Whh_f, Whh_b, zxq, hq);
    attnq_kernel<<<9, 32, 0, stream>>>(hq, W0, b0, attnq);
    expand_kernel<<<1, 256, 0, stream>>>(queries, attnq, attn);

    // steps 0+1 sparse, step 2 dense (norm fused into dense; all 3 ranks fused per block)
    hipMemsetAsync(mem2, 0, (size_t)NRANK * NENT * NB * sizeof(float), stream);
    hipMemsetAsync(normv, 0, NRANK * NB * sizeof(float), stream);
    {
        dim3 g(NB, NRANK, 2);
        fused01_kernel<<<g, 256, 0, stream>>>(heads, attn, fillS, eS, mem2);
    }
    {
        dim3 g(NPASS, NENT / 16);
        dense_kernel<<<g, 256, 0, stream>>>(attn, fillD, eD, mem2, mem3, normv);
    }

    // epilogue
    rnorm_kernel<<<1, NRANK * NB, 0, stream>>>(normv, rnormv);
    final_kernel<<<NENT / 32, 256, 0, stream>>>(mem3, rnormv, out);
}

// Round 14
// 1294.239 us; speedup vs baseline: 1.1074x; 1.1074x over previous
//
#include <hip/hip_runtime.h>

#define NENT 40000
#define NB 128
#define NQ 24
#define NOPS 12
#define EPO 300000
#define NTOT (NOPS * EPO)
#define NRANK 3
#define NPASS 8
#define CP 16       // batch columns per pass
#define ECAP 160    // ELL row capacity (Poisson(90) max over 40K rows << 160)

typedef float v4f __attribute__((ext_vector_type(4)));

__device__ __forceinline__ v4f shfl_xor4(v4f x, int m) {
    v4f r;
    r.x = __shfl_xor(x.x, m);
    r.y = __shfl_xor(x.y, m);
    r.z = __shfl_xor(x.z, m);
    r.w = __shfl_xor(x.w, m);
    return r;
}

__device__ __forceinline__ bool bittest(const unsigned* bm, int i) {
    return (bm[i >> 5] >> (i & 31)) & 1u;
}

// ---------------- bitmaps: heads and heads ∪ N_out(heads) ----------------
__global__ void headmark_kernel(const int* __restrict__ heads, unsigned* __restrict__ bmH,
                                unsigned* __restrict__ bm2) {
    int h = heads[threadIdx.x];
    atomicOr(&bmH[h >> 5], 1u << (h & 31));
    atomicOr(&bm2[h >> 5], 1u << (h & 31));
}

__global__ void mark2_kernel(const int* __restrict__ src, const int* __restrict__ dst,
                             const unsigned* __restrict__ bmH, unsigned* __restrict__ bm2) {
    int i = blockIdx.x * 256 + threadIdx.x;
    if (i < NTOT) {
        int s = src[i];
        if (bittest(bmH, s)) {
            int d = dst[i];
            atomicOr(&bm2[d >> 5], 1u << (d & 31));
        }
    }
}

// ---------------- single-pass ELL build: dst always; src gated on bm2 ----------------
__global__ void build_ell_kernel(const int* __restrict__ src, const int* __restrict__ dst,
                                 const float* __restrict__ val, const unsigned* __restrict__ bm2,
                                 int* __restrict__ fillD, int* __restrict__ fillS,
                                 int2* __restrict__ eD, int2* __restrict__ eS) {
    int i = blockIdx.x * 256 + threadIdx.x;
    if (i >= NTOT) return;
    int s = src[i], d = dst[i];
    int op = i / EPO;   // compile-time magic-mul
    int v = __float_as_int(val[i]);
    int pd = atomicAdd(&fillD[d], 1);
    eD[(size_t)d * ECAP + pd] = make_int2(s | (op << 16), v);
    if (bittest(bm2, s)) {
        int ps = atomicAdd(&fillS[s], 1);
        eS[(size_t)s * ECAP + ps] = make_int2(d | (op << 16), v);
    }
}

// ---------------- LSTM: zx-GEMV + 3 recurrent steps merged (deduped over 24 queries) ----------------
__global__ void lstm_all_kernel(const float* __restrict__ emb,
                                const float* __restrict__ Wih_f, const float* __restrict__ bih_f,
                                const float* __restrict__ bhh_f,
                                const float* __restrict__ Wih_b, const float* __restrict__ bih_b,
                                const float* __restrict__ bhh_b,
                                const float* __restrict__ Whh_f, const float* __restrict__ Whh_b,
                                float* __restrict__ hq) {
    int combo = blockIdx.x / NQ;
    int q = blockIdx.x % NQ;
    int dir = combo / 3, r = combo % 3;
    const float* Wih = (dir ? Wih_b : Wih_f) + r * 512 * 128;
    const float* bih = (dir ? bih_b : bih_f) + r * 512;
    const float* bhh = (dir ? bhh_b : bhh_f) + r * 512;
    const float* Whh = (dir ? Whh_b : Whh_f) + r * 512 * 128;
    __shared__ float x[128];
    __shared__ float h[128];
    int u = threadIdx.x;
    x[u] = emb[q * 128 + u];
    __syncthreads();
    const float* W0p = Wih + u * 128;
    const float* W1p = Wih + (128 + u) * 128;
    const float* W2p = Wih + (256 + u) * 128;
    const float* W3p = Wih + (384 + u) * 128;
    float a0 = 0.f, a1 = 0.f, a2 = 0.f, a3 = 0.f;
    for (int d = 0; d < 128; ++d) {
        float xv = x[d];
        a0 = fmaf(xv, W0p[d], a0);
        a1 = fmaf(xv, W1p[d], a1);
        a2 = fmaf(xv, W2p[d], a2);
        a3 = fmaf(xv, W3p[d], a3);
    }
    float zi0 = a0 + bih[u]       + bhh[u];
    float zf0 = a1 + bih[128 + u] + bhh[128 + u];
    float zg0 = a2 + bih[256 + u] + bhh[256 + u];
    float zo0 = a3 + bih[384 + u] + bhh[384 + u];
    const float* Wi = Whh + u * 128;
    const float* Wf = Whh + (128 + u) * 128;
    const float* Wg = Whh + (256 + u) * 128;
    const float* Wo = Whh + (384 + u) * 128;
    float c = 0.f;
    h[u] = 0.f;
    for (int s = 0; s < 3; ++s) {
        __syncthreads();
        float b0 = 0.f, b1 = 0.f, b2 = 0.f, b3 = 0.f;
        for (int d = 0; d < 128; ++d) {
            float hv = h[d];
            b0 = fmaf(hv, Wi[d], b0);
            b1 = fmaf(hv, Wf[d], b1);
            b2 = fmaf(hv, Wg[d], b2);
            b3 = fmaf(hv, Wo[d], b3);
        }
        float ig = 1.f / (1.f + expf(-(zi0 + b0)));
        float fg = 1.f / (1.f + expf(-(zf0 + b1)));
        float gg = tanhf(zg0 + b2);
        float og = 1.f / (1.f + expf(-(zo0 + b3)));
        c = fg * c + ig * gg;
        float hn = og * tanhf(c);
        __syncthreads();
        h[u] = hn;
        hq[(size_t)((combo * 3 + s) * NQ + q) * 128 + u] = hn;
    }
}

__global__ void attnq_kernel(const float* __restrict__ hq, const float* __restrict__ W0,
                             const float* __restrict__ b0, float* __restrict__ attnq) {
    int r = blockIdx.x / 3, t = blockIdx.x % 3;
    __shared__ float W0s[256 * 13];
    for (int idx = threadIdx.x; idx < 256 * 13; idx += 128) W0s[idx] = W0[idx];
    __syncthreads();
    int q = threadIdx.x;
    if (q >= NQ) return;
    float acc[13];
    for (int k = 0; k < 13; ++k) acc[k] = b0[k];
    const float* hf = hq + (size_t)(((0 * 3 + r) * 3 + t) * NQ + q) * 128;
    const float* hb = hq + (size_t)(((1 * 3 + r) * 3 + (2 - t)) * NQ + q) * 128;
    for (int u = 0; u < 128; ++u) {
        float v = hf[u];
        for (int k = 0; k < 13; ++k) acc[k] = fmaf(v, W0s[u * 13 + k], acc[k]);
    }
    for (int u = 0; u < 128; ++u) {
        float v = hb[u];
        for (int k = 0; k < 13; ++k) acc[k] = fmaf(v, W0s[(128 + u) * 13 + k], acc[k]);
    }
    float m = acc[0];
    for (int k = 1; k < 13; ++k) m = fmaxf(m, acc[k]);
    float e[13];
    float sum = 0.f;
    for (int k = 0; k < 13; ++k) { e[k] = expf(acc[k] - m); sum += e[k]; }
    float inv = 1.f / sum;
    float* ao = attnq + (size_t)(r * 3 + t) * 13 * NQ;
    for (int k = 0; k < 13; ++k) ao[k * NQ + q] = e[k] * inv;
}

// ---------------- steps 0+1, sparse expansion over ELL-S; writes pass-major mem[r][p][j][c] ----------------
// 256 threads, 8-lane groups per source entry; z-chunked grid for occupancy.
// Reads attnq directly via queries[b] (expand kernel eliminated).
__global__ void fused01_kernel(const int* __restrict__ heads, const int* __restrict__ queries,
                               const float* __restrict__ attnq,
                               const int* __restrict__ fillS, const int2* __restrict__ eS,
                               float* __restrict__ mem2) {
    int r = blockIdx.y;
    int b = blockIdx.x;
    int chunk = blockIdx.z;   // 0..1
    __shared__ float c0s[13], c1s[13];
    if (threadIdx.x < 13) {
        int qb = queries[b];
        c0s[threadIdx.x] = attnq[(size_t)((r * 3 + 0) * 13 + threadIdx.x) * NQ + qb];
        c1s[threadIdx.x] = attnq[(size_t)((r * 3 + 1) * 13 + threadIdx.x) * NQ + qb];
    }
    __syncthreads();
    int h = heads[b];
    int lenH = fillS[h];
    float* mem = mem2 + ((size_t)(r * NPASS + (b >> 4)) * NENT) * CP + (b & 15);
    int g = threadIdx.x >> 3, lane8 = threadIdx.x & 7;   // 32 groups of 8 lanes
    for (int ent = g + chunk * 32; ent < lenH + 1; ent += 64) {
        int i; float wv;
        if (ent == 0) { i = h; wv = c0s[12]; }
        else {
            int2 e = eS[(size_t)h * ECAP + ent - 1];
            i = e.x & 0xFFFF;
            wv = __int_as_float(e.y) * c0s[e.x >> 16];
        }
        if (lane8 == 0) atomicAdd(&mem[(size_t)i * CP], c1s[12] * wv);
        int lenI = fillS[i];
        const int2* ei = eS + (size_t)i * ECAP;
        for (int f = lane8; f < lenI; f += 8) {
            int2 e2 = ei[f];
            atomicAdd(&mem[(size_t)(e2.x & 0xFFFF) * CP],
                      __int_as_float(e2.y) * c1s[e2.x >> 16] * wv);
        }
    }
}

// ---------------- step 2: dense gather (R0 best-known: per-rank, 8-wide interleave) ----------------
__global__ __launch_bounds__(256) void dense_kernel(const int* __restrict__ queries,
                                                    const float* __restrict__ attnq,
                                                    const int* __restrict__ fillD,
                                                    const int2* __restrict__ edgesD,
                                                    const float* __restrict__ in,
                                                    float* __restrict__ out,
                                                    float* __restrict__ normv) {
    int p = blockIdx.x;   // pass = XCD (linear-id % 8 round-robin)
    int r = blockIdx.z;
    __shared__ __align__(16) float cs[13 * 20];   // stride 20 floats: rows 16B-aligned
    __shared__ float npart[4][16];
    int tid = threadIdx.x;
    if (tid < 13 * 16) {
        int op = tid >> 4, c0 = tid & 15;
        cs[op * 20 + c0] = attnq[(size_t)((r * 3 + 2) * 13 + op) * NQ + queries[p * CP + c0]];
    }
    __syncthreads();
    int wave = tid >> 6, lane = tid & 63;
    int slot = lane >> 2;        // 16 edge slots
    int cq4 = (lane & 3) * 4;    // 4 cols per lane
    int jw = blockIdx.y * 16 + wave * 4;   // 4 rows per wave
    const float* inr = in + (size_t)(r * NPASS + p) * NENT * CP;
    float* outr = out + (size_t)(r * NPASS + p) * NENT * CP;
    int lens[4];
    const int2* edp[4];
#pragma unroll
    for (int t = 0; t < 4; ++t) {
        lens[t] = fillD[jw + t];
        edp[t] = edgesD + (size_t)(jw + t) * ECAP;
    }
    int maxlen = max(max(lens[0], lens[1]), max(lens[2], lens[3]));
    v4f acc[4];
#pragma unroll
    for (int t = 0; t < 4; ++t) acc[t] = (v4f)0.f;

    // interleaved: 8 independent edge loads + 8 independent gathers per iteration
    for (int base = 0; base < maxlen; base += 32) {
        int2 e[8];
        bool m[8];
#pragma unroll
        for (int t = 0; t < 4; ++t) {
            int ia = base + slot;
            int ib = base + 16 + slot;
            m[t]     = ia < lens[t];
            m[4 + t] = ib < lens[t];
            e[t]     = edp[t][m[t] ? ia : 0];
            e[4 + t] = edp[t][m[4 + t] ? ib : 0];
        }
        v4f g[8];
#pragma unroll
        for (int u = 0; u < 8; ++u)
            g[u] = *(const v4f*)(inr + (size_t)(e[u].x & 0xFFFF) * CP + cq4);
#pragma unroll
        for (int u = 0; u < 8; ++u) {
            v4f cc = *(const v4f*)&cs[(e[u].x >> 16) * 20 + cq4];
            float v = m[u] ? __int_as_float(e[u].y) : 0.f;
            acc[u & 3] += (v * cc) * g[u];
        }
    }

    v4f cid = *(const v4f*)&cs[12 * 20 + cq4];
    v4f rsum = (v4f)0.f;
#pragma unroll
    for (int t = 0; t < 4; ++t) {
        v4f red = acc[t];
        red += shfl_xor4(red, 4);
        red += shfl_xor4(red, 8);
        red += shfl_xor4(red, 16);
        red += shfl_xor4(red, 32);
        if (slot == 0) {
            int j = jw + t;
            v4f mi = *(const v4f*)(inr + (size_t)j * CP + cq4);
            v4f res = cid * mi + red;
            *(v4f*)(outr + (size_t)j * CP + cq4) = res;
            rsum += res;
        }
    }
    if (slot == 0) *(v4f*)&npart[wave][cq4] = rsum;
    __syncthreads();
    if (tid < 16) {
        float s = npart[0][tid] + npart[1][tid] + npart[2][tid] + npart[3][tid];
        atomicAdd(&normv[r * 128 + p * CP + tid], s);
    }
}

// ---------------- epilogue (rnorm fused in) ----------------
__global__ void final_kernel(const float* __restrict__ mem3, const float* __restrict__ normv,
                             float* __restrict__ out) {
    __shared__ float tile[32 * 129];
    __shared__ float rn[384];
    for (int idx = threadIdx.x; idx < 384; idx += 256)
        rn[idx] = 1.f / fmaxf(normv[idx], 1e-20f);
    __syncthreads();
    int j0 = blockIdx.x * 32;
    for (int p = 0; p < NPASS; ++p) {
        for (int it = 0; it < 2; ++it) {
            int lin = it * 256 + threadIdx.x;
            int jj = lin >> 4, c = lin & 15;
            int b = p * CP + c;
            float s = 0.f;
            for (int r = 0; r < 3; ++r)
                s += mem3[((size_t)(r * NPASS + p) * NENT + j0 + jj) * CP + c] * rn[r * 128 + b];
            tile[jj * 129 + b] = s;
        }
    }
    __syncthreads();
    for (int it = 0; it < 16; ++it) {
        int lin = it * 256 + threadIdx.x;
        int b = lin >> 5, jj = lin & 31;
        out[(size_t)b * NENT + j0 + jj] = tile[jj * 129 + b];
    }
}

extern "C" void kernel_launch(void* const* d_in, const int* in_sizes, int n_in,
                              void* d_out, int out_size, void* d_ws, size_t ws_size,
                              hipStream_t stream) {
    const int*   queries  = (const int*)d_in[0];
    const int*   heads    = (const int*)d_in[1];
    const int*   edge_src = (const int*)d_in[2];
    const int*   edge_dst = (const int*)d_in[3];
    const float* edge_val = (const float*)d_in[4];
    const float* emb      = (const float*)d_in[5];
    const float* Wih_f    = (const float*)d_in[6];
    const float* Whh_f    = (const float*)d_in[7];
    const float* bih_f    = (const float*)d_in[8];
    const float* bhh_f    = (const float*)d_in[9];
    const float* Wih_b    = (const float*)d_in[10];
    const float* Whh_b    = (const float*)d_in[11];
    const float* bih_b    = (const float*)d_in[12];
    const float* bhh_b    = (const float*)d_in[13];
    const float* W0       = (const float*)d_in[14];
    const float* b0       = (const float*)d_in[15];
    float* out = (float*)d_out;

    char* w = (char*)d_ws;
    size_t off = 0;
    auto alloc = [&](size_t bytes) -> void* {
        off = (off + 255) & ~(size_t)255;
        void* p = w + off;
        off += bytes;
        return p;
    };
    float* attnq  = (float*)alloc((size_t)9 * 13 * NQ * sizeof(float));
    float* hq     = (float*)alloc((size_t)6 * 3 * NQ * 128 * sizeof(float));
    // meta block (single memset): bmH | bm2 | fillD | fillS
    unsigned* bmH = (unsigned*)alloc((2 * 1250 + 2 * NENT) * sizeof(int));
    unsigned* bm2 = bmH + 1250;
    int* fillD    = (int*)(bm2 + 1250);
    int* fillS    = fillD + NENT;
    int2*  eD     = (int2*)alloc((size_t)NENT * ECAP * sizeof(int2));
    float* mem2   = (float*)alloc((size_t)NRANK * NENT * NB * sizeof(float));
    float* mem3   = (float*)alloc((size_t)NRANK * NENT * NB * sizeof(float));
    int2*  eS     = (int2*)mem3;   // alias: eS lifetime (build..fused01) ends before mem3's (dense..final)
    float* normv  = (float*)alloc((size_t)NRANK * NB * sizeof(float));

    int cooGrid = (NTOT + 255) / 256;

    // bitmaps + fills (one memset), then single-pass ELL build
    hipMemsetAsync(bmH, 0, (2 * 1250 + 2 * NENT) * sizeof(int), stream);
    headmark_kernel<<<1, 128, 0, stream>>>(heads, bmH, bm2);
    mark2_kernel<<<cooGrid, 256, 0, stream>>>(edge_src, edge_dst, bmH, bm2);
    build_ell_kernel<<<cooGrid, 256, 0, stream>>>(edge_src, edge_dst, edge_val, bm2,
                                                  fillD, fillS, eD, eS);

    // LSTM + attention (deduped over 24 queries; zx-GEMV + recurrence merged)
    lstm_all_kernel<<<6 * NQ, 128, 0, stream>>>(emb, Wih_f, bih_f, bhh_f,
                                                Wih_b, bih_b, bhh_b, Whh_f, Whh_b, hq);
    attnq_kernel<<<9, 128, 0, stream>>>(hq, W0, b0, attnq);

    // steps 0+1 sparse, step 2 dense (norm fused into dense)
    hipMemsetAsync(mem2, 0, (size_t)NRANK * NENT * NB * sizeof(float), stream);
    hipMemsetAsync(normv, 0, NRANK * NB * sizeof(float), stream);
    {
        dim3 g(NB, NRANK, 2);
        fused01_kernel<<<g, 256, 0, stream>>>(heads, queries, attnq, fillS, eS, mem2);
    }
    {
        dim3 g(NPASS, NENT / 16, NRANK);
        dense_kernel<<<g, 256, 0, stream>>>(queries, attnq, fillD, eD, mem2, mem3, normv);
    }

    // epilogue
    final_kernel<<<NENT / 32, 256, 0, stream>>>(mem3, normv, out);
}